// Round 1
// 328.450 us; speedup vs baseline: 1.0167x; 1.0167x over previous
//
#include <hip/hip_runtime.h>
#include <stdint.h>

// XLA emits multiply and add as separate uncontracted HLOs; HIP's default
// -ffp-contract=fast would fuse them into fma and break bit-exact RNG/score
// reproduction. Kill contraction globally.
#pragma clang fp contract(off)

// ---- Threefry-2x32, 20 rounds, exact JAX schedule ----
__host__ __device__ inline void tf2x32(uint32_t k0, uint32_t k1,
                                       uint32_t x0, uint32_t x1,
                                       uint32_t* o0, uint32_t* o1) {
  const uint32_t ks2 = k0 ^ k1 ^ 0x1BD11BDAu;
  x0 += k0; x1 += k1;
#define TF_R(r) { x0 += x1; x1 = (x1 << (r)) | (x1 >> (32 - (r))); x1 ^= x0; }
  TF_R(13) TF_R(15) TF_R(26) TF_R(6)
  x0 += k1;  x1 += ks2 + 1u;
  TF_R(17) TF_R(29) TF_R(16) TF_R(24)
  x0 += ks2; x1 += k0 + 2u;
  TF_R(13) TF_R(15) TF_R(26) TF_R(6)
  x0 += k0;  x1 += k1 + 3u;
  TF_R(17) TF_R(29) TF_R(16) TF_R(24)
  x0 += k1;  x1 += ks2 + 4u;
  TF_R(13) TF_R(15) TF_R(26) TF_R(6)
  x0 += ks2; x1 += k0 + 5u;
#undef TF_R
  *o0 = x0; *o1 = x1;
}

// ---- XLA ErfInv32 (Giles coefficients, exact op order) ----
__device__ inline float erfinv_xla(float x) {
#pragma clang fp contract(off)
  float w = -log1pf(-(x * x));
  float p;
  if (w < 5.0f) {
    w = w - 2.5f;
    p = 2.81022636e-08f;
    p = 3.43273939e-07f  + p * w;
    p = -3.5233877e-06f  + p * w;
    p = -4.39150654e-06f + p * w;
    p = 0.00021858087f   + p * w;
    p = -0.00125372503f  + p * w;
    p = -0.00417768164f  + p * w;
    p = 0.246640727f     + p * w;
    p = 1.50140941f      + p * w;
  } else {
    w = sqrtf(w) - 3.0f;
    p = -0.000200214257f;
    p = 0.000100950558f  + p * w;
    p = 0.00134934322f   + p * w;
    p = -0.00367342844f  + p * w;
    p = 0.00573950773f   + p * w;
    p = -0.0076224613f   + p * w;
    p = 0.00943887047f   + p * w;
    p = 1.00167406f      + p * w;
    p = 2.83297682f      + p * w;
  }
  return p * x;
}

// jax.random.normal element `idx` under key (k0,k1), partitionable stream.
__device__ inline float jax_normal(uint32_t k0, uint32_t k1, uint32_t idx) {
#pragma clang fp contract(off)
  uint32_t o0, o1;
  tf2x32(k0, k1, 0u, idx, &o0, &o1);
  uint32_t bits = o0 ^ o1;
  float f = __uint_as_float((bits >> 9) | 0x3f800000u) - 1.0f;
  float u = f * 2.0f + (-0x1.fffffep-1f);
  u = fmaxf(-0x1.fffffep-1f, u);
  return 0x1.6a09e6p+0f * erfinv_xla(u);  // float(sqrt(2)) * erfinv(u)
}

// Bilinear corr score; association matches XLA: ((t00+t01)+t10)+t11.
__device__ inline float score_at(const float* __restrict__ base, int stride,
                                 float x, float y) {
#pragma clang fp contract(off)
  float x0 = floorf(x), y0 = floorf(y);
  float wx = x - x0, wy = y - y0;
  int xi = (int)x0; xi = xi < 0 ? 0 : (xi > 63 ? 63 : xi);
  int yi = (int)y0; yi = yi < 0 ? 0 : (yi > 63 ? 63 : yi);
  int x1 = xi + 1 > 63 ? 63 : xi + 1;
  int y1 = yi + 1 > 63 ? 63 : yi + 1;
  float v00 = base[(yi * 64 + xi) * stride];
  float v01 = base[(yi * 64 + x1) * stride];
  float v10 = base[(y1 * 64 + xi) * stride];
  float v11 = base[(y1 * 64 + x1) * stride];
  float omx = 1.0f - wx, omy = 1.0f - wy;
  return (((v00 * omx) * omy + (v01 * wx) * omy) + (v10 * omx) * wy) + (v11 * wx) * wy;
}

// One propagate(+optional random-search) evaluation at a single pixel.
// Bit-exact to the reference: nh/nv are the pre-roll neighbor coords; dx is
// added to the h-candidate's x, dy to the v-candidate's y (y/x clamps of the
// other component are no-ops since all stored coords are already in range).
// Carried own_s == score_at(own) bit-exactly (same pure function).
__device__ inline float4 prop_rs(float2 own, float own_s, float2 nh, float2 nv,
                                 float fdx, float fdy,
                                 const float* __restrict__ base, int stride,
                                 bool do_rs, uint32_t k0, uint32_t k1,
                                 uint32_t pg) {
#pragma clang fp contract(off)
  float chx = fminf(fmaxf(nh.x + fdx, 0.0f), 63.0f);
  float chy = nh.y;
  float cvx = nv.x;
  float cvy = fminf(fmaxf(nv.y + fdy, 0.0f), 63.0f);
  float2 bst = own; float bs = own_s;
  float sh = score_at(base, stride, chx, chy);
  float sv = score_at(base, stride, cvx, cvy);
  if (sh > bs) bst = make_float2(chx, chy);   // upd = s > best_s
  bs = fmaxf(sh, bs);
  if (sv > bs) bst = make_float2(cvx, cvy);
  bs = fmaxf(sv, bs);
  if (do_rs) {
    float n0 = jax_normal(k0, k1, 2u * pg);
    float n1 = jax_normal(k0, k1, 2u * pg + 1u);
    float nx = fminf(fmaxf(bst.x + 3.0f * n0, 0.0f), 63.0f);
    float ny = fminf(fmaxf(bst.y + 3.0f * n1, 0.0f), 63.0f);
    float sn = score_at(base, stride, nx, ny);
    if (sn - bs > 0.0f) { bst = make_float2(nx, ny); bs = sn; }  // new_s - 1.0*old_s > 0
  }
  return make_float4(bst.x, bst.y, bs, 0.0f);
}

// All four propagate/random-search steps fused into ONE kernel via
// tile-recompute: each block owns one 8x8 output tile of one (dir,b) image
// and recomputes the dependency cone in LDS (halo rectangles 11x11 -> 10x10
// -> 9x9 -> 8x8; intra-block __syncthreads only, no global barrier).
// Step offsets (prev-pixel reads), derived from roll semantics
// (jh=(j-dx)&63, iv=(i-dy)&63):
//   step1 (dx=+1,dy=+1): (i,j),(i,j-1),(i-1,j)   from matching
//   step2 (dx=-1,dy=-1): (i,j),(i,j+1),(i+1,j)   from step1
//   step3 (dx=-1,dy=+1): (i,j),(i,j+1),(i-1,j)   from step2
//   step4 (dx=+1,dy=-1): (i,j),(i,j-1),(i+1,j)   from step3
// Halo evals are bit-identical to what the per-step kernels computed at those
// pixels (same pure function, same per-pixel Threefry stream), so the fusion
// is exact by induction. ~1.46x tap amplification; redundant taps are L2/L3
// hits (same distinct lines), so HBM traffic is ~unchanged.
__global__ __launch_bounds__(64) void fused_kernel(
    const float* __restrict__ mf, const float* __restrict__ mb,
    const float* __restrict__ corr, float2* __restrict__ res,
    uint32_t f10, uint32_t f11, uint32_t f20, uint32_t f21,
    uint32_t f30, uint32_t f31,
    uint32_t b10, uint32_t b11, uint32_t b20, uint32_t b21,
    uint32_t b30, uint32_t b31) {
#pragma clang fp contract(off)
  const int bx  = (int)blockIdx.x;        // 0..511 = 2 dir x 4 b x 64 tiles
  const int dir = bx >> 8;
  const int b   = (bx >> 6) & 3;
  const int tile = bx & 63;
  const int i0 = (tile >> 3) << 3;
  const int j0 = (tile & 7) << 3;
  const int tid = (int)threadIdx.x;

  const float* __restrict__ m = dir ? mb : mf;
  const uint32_t k10 = dir ? b10 : f10, k11 = dir ? b11 : f11;
  const uint32_t k20 = dir ? b20 : f20, k21 = dir ? b21 : f21;
  const uint32_t k30 = dir ? b30 : f30, k31 = dir ? b31 : f31;
  const int    stride  = dir ? 4096 : 1;
  const size_t pstride = dir ? 1 : 4096;
  const float* __restrict__ corrb = corr + (size_t)b * 16777216u;
  const float* __restrict__ mx = m + (size_t)((b * 2 + 0) * 64) * 64;
  const float* __restrict__ my = m + (size_t)((b * 2 + 1) * 64) * 64;

  __shared__ float4 S1[121];   // origin (i0-1, j0-1), 11x11
  __shared__ float4 S2[100];   // origin (i0-1, j0-1), 10x10
  __shared__ float4 S3[81];    // origin (i0,   j0-1),  9x9

  // ---- step1: propagate(+1,+1) from matching + RS(k1) over 11x11 halo
  for (int idx = tid; idx < 121; idx += 64) {
    int r = idx / 11, c = idx - r * 11;
    int ii = (i0 - 1 + r) & 63, jj = (j0 - 1 + c) & 63;
    int p = (ii << 6) | jj;
    const float* base = corrb + (size_t)p * pstride;
    int jh = (jj - 1) & 63, iv = (ii - 1) & 63;
    float2 own = make_float2(mx[(ii << 6) | jj], my[(ii << 6) | jj]);
    float2 nh  = make_float2(mx[(ii << 6) | jh], my[(ii << 6) | jh]);
    float2 nv  = make_float2(mx[(iv << 6) | jj], my[(iv << 6) | jj]);
    float own_s = score_at(base, stride, own.x, own.y);
    S1[idx] = prop_rs(own, own_s, nh, nv, 1.0f, 1.0f, base, stride,
                      true, k10, k11, (uint32_t)((b << 12) | p));
  }
  __syncthreads();

  // ---- step2: propagate(-1,-1) + RS(k2) over 10x10 (same origin as S1)
  for (int idx = tid; idx < 100; idx += 64) {
    int r = idx / 10, c = idx - r * 10;
    int ii = (i0 - 1 + r) & 63, jj = (j0 - 1 + c) & 63;
    int p = (ii << 6) | jj;
    const float* base = corrb + (size_t)p * pstride;
    float4 o = S1[r * 11 + c];          // (i, j)
    float4 h = S1[r * 11 + c + 1];      // (i, j+1)
    float4 v = S1[(r + 1) * 11 + c];    // (i+1, j)
    S2[idx] = prop_rs(make_float2(o.x, o.y), o.z,
                      make_float2(h.x, h.y), make_float2(v.x, v.y),
                      -1.0f, -1.0f, base, stride,
                      true, k20, k21, (uint32_t)((b << 12) | p));
  }
  __syncthreads();

  // ---- step3: propagate(-1,+1) + RS(k3) over 9x9, origin (i0, j0-1)
  for (int idx = tid; idx < 81; idx += 64) {
    int r = idx / 9, c = idx - r * 9;
    int ii = (i0 + r) & 63, jj = (j0 - 1 + c) & 63;
    int p = (ii << 6) | jj;
    const float* base = corrb + (size_t)p * pstride;
    // abs (ii,jj) at S2-local (r+1, c)
    float4 o = S2[(r + 1) * 10 + c];        // (i, j)
    float4 h = S2[(r + 1) * 10 + c + 1];    // (i, j+1)
    float4 v = S2[r * 10 + c];              // (i-1, j)
    S3[idx] = prop_rs(make_float2(o.x, o.y), o.z,
                      make_float2(h.x, h.y), make_float2(v.x, v.y),
                      -1.0f, 1.0f, base, stride,
                      true, k30, k31, (uint32_t)((b << 12) | p));
  }
  __syncthreads();

  // ---- step4: propagate(+1,-1), no RS; write final coords (float2)
  {
    int r = tid >> 3, c = tid & 7;
    int ii = i0 + r, jj = j0 + c;
    int p = (ii << 6) | jj;
    const float* base = corrb + (size_t)p * pstride;
    // abs (ii,jj) at S3-local (r, c+1)
    float4 o = S3[r * 9 + c + 1];           // (i, j)
    float4 h = S3[r * 9 + c];               // (i, j-1)
    float4 v = S3[(r + 1) * 9 + c + 1];     // (i+1, j)
    float4 fin = prop_rs(make_float2(o.x, o.y), o.z,
                         make_float2(h.x, h.y), make_float2(v.x, v.y),
                         1.0f, -1.0f, base, stride, false, 0u, 0u, 0u);
    res[(dir << 14) | (b << 12) | p] = make_float2(fin.x, fin.y);
  }
}

// Bilinear-sample res_b at res_f, fwd-bwd consistency, transpose to (B,2,H,W).
__global__ __launch_bounds__(256) void combine_kernel(const float* __restrict__ mf,
                                                      const float2* __restrict__ res,
                                                      float* __restrict__ out) {
#pragma clang fp contract(off)
  int pg = (int)(blockIdx.x * 256 + threadIdx.x);   // 0..16383
  int b = pg >> 12, hw = pg & 4095;
  int i = hw >> 6, j = hw & 63;
  float2 rf = res[pg];
  const float2* rb = res + 16384 + (b << 12);
  float x0 = floorf(rf.x), y0 = floorf(rf.y);
  float wx = rf.x - x0, wy = rf.y - y0;
  int xi = (int)x0; xi = xi < 0 ? 0 : (xi > 63 ? 63 : xi);
  int yi = (int)y0; yi = yi < 0 ? 0 : (yi > 63 ? 63 : yi);
  int x1 = xi + 1 > 63 ? 63 : xi + 1;
  int y1 = yi + 1 > 63 ? 63 : yi + 1;
  float2 v00 = rb[yi * 64 + xi], v01 = rb[yi * 64 + x1];
  float2 v10 = rb[y1 * 64 + xi], v11 = rb[y1 * 64 + x1];
  float omx = 1.0f - wx, omy = 1.0f - wy;
  float c0 = (((v00.x * omx) * omy + (v01.x * wx) * omy) + (v10.x * omx) * wy) + (v11.x * wx) * wy;
  float c1 = (((v00.y * omx) * omy + (v01.y * wx) * omy) + (v10.y * omx) * wy) + (v11.y * wx) * wy;
  float d = fmaxf(fabsf(rf.x - c0), fabsf(rf.y - c1));
  bool invalid = d > 0.01f;
  out[((b * 2 + 0) * 64 + i) * 64 + j] = invalid ? mf[((b * 2 + 0) * 64 + i) * 64 + j] : rf.x;
  out[((b * 2 + 1) * 64 + i) * 64 + j] = invalid ? mf[((b * 2 + 1) * 64 + i) * 64 + j] : rf.y;
}

extern "C" void kernel_launch(void* const* d_in, const int* in_sizes, int n_in,
                              void* d_out, int out_size, void* d_ws, size_t ws_size,
                              hipStream_t stream) {
  const float* mf   = (const float*)d_in[0];
  const float* mb   = (const float*)d_in[1];
  const float* corr = (const float*)d_in[2];
  float* out  = (float*)d_out;
  float2* res = (float2*)d_ws;              // [2][4][4096] float2 = 256 KB

  // Host-side key derivation from seed 42 -> root key (0, 42).
  // split(root,2)[d] = enc_root(0, d); split(k,3)[s] = enc_k(0, s).
  uint32_t kf0, kf1, kb0, kb1, K[12];
  tf2x32(0u, 42u, 0u, 0u, &kf0, &kf1);
  tf2x32(0u, 42u, 0u, 1u, &kb0, &kb1);
  for (uint32_t s = 0; s < 3; ++s) {
    tf2x32(kf0, kf1, 0u, s, &K[0 + s * 2], &K[0 + s * 2 + 1]);
    tf2x32(kb0, kb1, 0u, s, &K[6 + s * 2], &K[6 + s * 2 + 1]);
  }

  fused_kernel<<<dim3(512), dim3(64), 0, stream>>>(
      mf, mb, corr, res,
      K[0], K[1], K[2], K[3], K[4], K[5],
      K[6], K[7], K[8], K[9], K[10], K[11]);
  combine_kernel<<<dim3(64), dim3(256), 0, stream>>>(mf, res, out);
  (void)in_sizes; (void)n_in; (void)out_size; (void)ws_size;
}